// Round 1
// baseline (638.244 us; speedup 1.0000x reference)
//
#include <hip/hip_runtime.h>
#include <cstdint>
#include <cstddef>

#define DEVI __device__ __forceinline__

typedef short bf16x8 __attribute__((ext_vector_type(8)));
typedef short bf16x4 __attribute__((ext_vector_type(4)));
typedef float f32x4  __attribute__((ext_vector_type(4)));

constexpr int H_  = 2048;
constexpr int NH  = 16;
constexpr int NKV = 4;
constexpr int HD  = 128;
constexpr int B_  = 4;
constexpr int QL  = 1024;
constexpr int CL  = 3072;
constexpr int KL  = 4096;   // CL + QL
constexpr float EPS = 1e-6f;
// SCALE * log2(e): folded into stored Q so attention softmax is bare exp2
constexpr float SCALE_LOG2E = 0.08838834764831845f * 1.4426950408889634f;

DEVI unsigned short f2bf(float x) {
  unsigned int u = __float_as_uint(x);
  u += 0x7FFFu + ((u >> 16) & 1u);   // RNE
  return (unsigned short)(u >> 16);
}
DEVI float bf2f(unsigned short u) {
  return __uint_as_float(((unsigned int)u) << 16);
}
// pack 4 fp32 -> 4 bf16 with round-half-up (cheap: add + v_perm)
DEVI bf16x4 mk4(float a, float b, float c, float d) {
  unsigned ua = __float_as_uint(a) + 0x8000u, ub = __float_as_uint(b) + 0x8000u;
  unsigned uc = __float_as_uint(c) + 0x8000u, ud = __float_as_uint(d) + 0x8000u;
  union { unsigned u[2]; bf16x4 v; } r;
  r.u[0] = __builtin_amdgcn_perm(ub, ua, 0x07060302u);  // hi16(b):hi16(a)
  r.u[1] = __builtin_amdgcn_perm(ud, uc, 0x07060302u);
  return r.v;
}

DEVI void async16(const void* g, void* l) {
  __builtin_amdgcn_global_load_lds(
      (const __attribute__((address_space(1))) void*)g,
      (__attribute__((address_space(3))) void*)l, 16, 0, 0);
}

// ---------------------------------------------------------------------------
// prep: kvin_bf[b][pos][h] = bf16(concat(ctx, noise))   (b, KL, H)
// ---------------------------------------------------------------------------
__global__ __launch_bounds__(256)
void prep(const float* __restrict__ noise, const float* __restrict__ ctx,
          unsigned short* __restrict__ kvin) {
  const size_t t = (size_t)blockIdx.x * 256 + threadIdx.x;   // one 8-elem chunk
  const size_t e = t * 8;
  const int row = (int)(e / H_), col = (int)(e % H_);
  const int b = row >> 12, pos = row & 4095;
  const float* src = (pos < CL) ? ctx + ((size_t)(b * CL + pos)) * H_ + col
                                : noise + ((size_t)(b * QL + (pos - CL))) * H_ + col;
  float4 x = ((const float4*)src)[0], y = ((const float4*)src)[1];
  bf16x8 v;
  v[0] = (short)f2bf(x.x); v[1] = (short)f2bf(x.y);
  v[2] = (short)f2bf(x.z); v[3] = (short)f2bf(x.w);
  v[4] = (short)f2bf(y.x); v[5] = (short)f2bf(y.y);
  v[6] = (short)f2bf(y.z); v[7] = (short)f2bf(y.w);
  *(bf16x8*)(kvin + e) = v;
}

// ---------------------------------------------------------------------------
// Weight transpose + fp32 -> bf16:  in (K x N) fp32  ->  out (N x K) bf16
// ---------------------------------------------------------------------------
__global__ __launch_bounds__(256)
void wtrans(const float* __restrict__ in, unsigned short* __restrict__ out,
            int K, int N) {
  __shared__ float t[64][65];
  const int ktiles = K >> 6;
  const int kt = blockIdx.x % ktiles;
  const int nt = blockIdx.x / ktiles;
  {
    const int r = threadIdx.x >> 2, cs = threadIdx.x & 3;
    const float4* src = (const float4*)(in + (size_t)(kt * 64 + r) * N + nt * 64 + cs * 16);
    #pragma unroll
    for (int i = 0; i < 4; ++i) {
      float4 v = src[i];
      t[r][cs * 16 + i * 4 + 0] = v.x;
      t[r][cs * 16 + i * 4 + 1] = v.y;
      t[r][cs * 16 + i * 4 + 2] = v.z;
      t[r][cs * 16 + i * 4 + 3] = v.w;
    }
  }
  __syncthreads();
  {
    const int n = threadIdx.x >> 2, ks = threadIdx.x & 3;
    bf16x8 o0, o1;
    #pragma unroll
    for (int i = 0; i < 8; ++i) o0[i] = (short)f2bf(t[ks * 16 + i][n]);
    #pragma unroll
    for (int i = 0; i < 8; ++i) o1[i] = (short)f2bf(t[ks * 16 + 8 + i][n]);
    unsigned short* op = out + (size_t)(nt * 64 + n) * K + kt * 64 + ks * 16;
    *(bf16x8*)(op) = o0;
    *(bf16x8*)(op + 8) = o1;
  }
}

// ---------------------------------------------------------------------------
// m97-style GEMM, both operands bf16 via global_load_lds w/ XOR granule swizzle.
// C(M x N) = A(M x 2048) @ B(2048 x N), B given transposed (N x K) bf16.
// MODE 0: A=kvin rows (b,CL+q)  -> rmsnorm+rope, *SCALE_LOG2E -> q  (b,h,q,d)
// MODE 1: A=kvin                -> rmsnorm+rope -> k  (b,kv,p,d)
// MODE 2: A=kvin                -> transpose    -> vT (b,kv,d,p)
// MODE 3: A=attn_out bf16       -> fp32 d_out
// ---------------------------------------------------------------------------
template <int MODE>
__global__ __launch_bounds__(256)
void gemm2(const unsigned short* __restrict__ Abf,
           const unsigned short* __restrict__ Bt,
           const float* __restrict__ normw,
           const float* __restrict__ cosb, const float* __restrict__ sinb,
           unsigned short* __restrict__ outb, float* __restrict__ outf) {
  constexpr int M  = (MODE == 1 || MODE == 2) ? (B_ * KL) : (B_ * QL);
  constexpr int K  = H_;
  constexpr int MT = M / 128;

  __shared__ union U {
    struct { unsigned short a[128][64]; unsigned short b[128][64]; } st; // 32 KB
    unsigned short ct[128][138];                                         // 35.3 KB
  } sm;

  const int tid  = threadIdx.x;
  const int tm   = blockIdx.x % MT;
  const int tn   = blockIdx.x / MT;
  const int wid  = tid >> 6, lane = tid & 63, quad = lane >> 4, lm = lane & 15;
  const int wm   = wid >> 1, wn = wid & 1;

  f32x4 acc[4][4];
  #pragma unroll
  for (int i = 0; i < 4; ++i)
    #pragma unroll
    for (int j = 0; j < 4; ++j)
      #pragma unroll
      for (int r = 0; r < 4; ++r) acc[i][j][r] = 0.f;

  // staging pointers (per 16B granule; LDS side is linear: offset 16*idx)
  const unsigned short* agp[4];
  const unsigned short* bgp[4];
  #pragma unroll
  for (int i = 0; i < 4; ++i) {
    const int idx = i * 256 + tid;
    const int arow = idx >> 3, g = idx & 7, gg = g ^ (arow & 7);
    int grow;
    if constexpr (MODE == 0) {
      const int gmr = tm * 128 + arow;
      grow = (gmr >> 10) * KL + CL + (gmr & 1023);
    } else {
      grow = tm * 128 + arow;
    }
    agp[i] = Abf + (size_t)grow * K + gg * 8;
    bgp[i] = Bt + (size_t)(tn * 128 + arow) * K + gg * 8;
  }

  for (int kt = 0; kt < K / 64; ++kt) {
    __syncthreads();
    #pragma unroll
    for (int i = 0; i < 4; ++i) {
      async16(agp[i] + kt * 64, (char*)&sm.st.a[0][0] + (i * 256 + wid * 64) * 16);
      async16(bgp[i] + kt * 64, (char*)&sm.st.b[0][0] + (i * 256 + wid * 64) * 16);
    }
    __syncthreads();
    #pragma unroll
    for (int ks = 0; ks < 2; ++ks) {
      bf16x8 af[4], bfr[4];
      #pragma unroll
      for (int i = 0; i < 4; ++i) {
        const int swz = (ks * 4 + quad) ^ (lm & 7);
        af[i] = *(const bf16x8*)&sm.st.a[wm * 64 + i * 16 + lm][swz * 8];
      }
      #pragma unroll
      for (int j = 0; j < 4; ++j) {
        const int swz = (ks * 4 + quad) ^ (lm & 7);
        bfr[j] = *(const bf16x8*)&sm.st.b[wn * 64 + j * 16 + lm][swz * 8];
      }
      #pragma unroll
      for (int i = 0; i < 4; ++i)
        #pragma unroll
        for (int j = 0; j < 4; ++j)
          acc[i][j] = __builtin_amdgcn_mfma_f32_16x16x32_bf16(af[i], bfr[j], acc[i][j], 0, 0, 0);
    }
  }

  if constexpr (MODE == 3) {
    #pragma unroll
    for (int i = 0; i < 4; ++i)
      #pragma unroll
      for (int j = 0; j < 4; ++j) {
        const int row = tm * 128 + wm * 64 + i * 16 + quad * 4;
        const int col = tn * 128 + wn * 64 + j * 16 + lm;
        #pragma unroll
        for (int rr = 0; rr < 4; ++rr)
          outf[(size_t)(row + rr) * H_ + col] = acc[i][j][rr];
      }
    return;
  }

  // C tile -> LDS bf16
  __syncthreads();
  #pragma unroll
  for (int i = 0; i < 4; ++i)
    #pragma unroll
    for (int j = 0; j < 4; ++j)
      #pragma unroll
      for (int rr = 0; rr < 4; ++rr)
        sm.ct[wm * 64 + i * 16 + quad * 4 + rr][wn * 64 + j * 16 + lm] =
            f2bf(acc[i][j][rr]);
  __syncthreads();

  const int row2 = tid >> 1, half = tid & 1;
  if constexpr (MODE == 0 || MODE == 1) {
    const int gmr = tm * 128 + row2;
    int ci; size_t obase;
    if constexpr (MODE == 0) {
      const int b = gmr >> 10, pos = gmr & 1023;
      ci = (b * KL + CL + pos) * HD;
      obase = ((size_t)((b * NH + tn) * QL + pos)) * HD;
    } else {
      const int b = gmr >> 12, pos = gmr & 4095;
      ci = (b * KL + pos) * HD;
      obase = ((size_t)((b * NKV + tn) * KL + pos)) * HD;
    }
    float ss = 0.f;
    for (int d = half * 64; d < half * 64 + 64; ++d) {
      float v = bf2f(sm.ct[row2][d]);
      ss += v * v;
    }
    ss += __shfl_xor(ss, 1);
    const float rinv = rsqrtf(ss * (1.0f / 128.0f) + EPS);
    constexpr float OSC = (MODE == 0) ? SCALE_LOG2E : 1.0f;
    #pragma unroll
    for (int d8 = 0; d8 < 8; ++d8) {
      bf16x8 v;
      #pragma unroll
      for (int j = 0; j < 8; ++j) {
        const int d = half * 64 + d8 * 8 + j;
        const float x  = bf2f(sm.ct[row2][d])      * rinv * normw[d];
        const float xo = bf2f(sm.ct[row2][d ^ 64]) * rinv * normw[d ^ 64];
        const float rot = (d < 64) ? -xo : xo;
        v[j] = (short)f2bf((x * cosb[ci + d] + rot * sinb[ci + d]) * OSC);
      }
      *(bf16x8*)(outb + obase + half * 64 + d8 * 8) = v;
    }
  } else {
    // MODE 2: V^T  (b, kv, d, pos)
    const int d = row2;
    const int b = (tm * 128) >> 12;
    const int posBase = ((tm * 128) & 4095) + half * 64;
    const size_t obase = ((size_t)((b * NKV + tn) * HD + d)) * KL + posBase;
    #pragma unroll
    for (int k8 = 0; k8 < 8; ++k8) {
      bf16x8 v;
      #pragma unroll
      for (int j = 0; j < 8; ++j)
        v[j] = (short)sm.ct[half * 64 + k8 * 8 + j][d];
      *(bf16x8*)(outb + obase + k8 * 8) = v;
    }
  }
}

// ---------------------------------------------------------------------------
// Flash attention v2.  Block = one (b,h) x 64 q rows; 4 waves x 16 q rows.
// Grid = 4*16 heads x 16 qblks = 1024 blocks -> 4 blocks/CU, 16 waves/CU
// (was 512 blocks / 8 waves/CU: MfmaUtil 49 + VALUBusy 52 ~ serialized pipes;
//  occupancy was grid-limited at 20%).
// S^T = K Q^T (16x16x32) -> p = exp2(s) in regs -> O^T += V^T P^T (16x16x16,
// P^T taken directly from S^T's C-layout registers).  No-max softmax
// (|s|<=16.3 in exp2 domain, bounded by RMSNorm), li reduced once at end.
// K/V tiles staged via global_load_lds with XOR granule swizzle.
// s_setprio(1) wraps MFMA clusters (T5: cross-block phase diversity now exists).
// ---------------------------------------------------------------------------
__global__ __launch_bounds__(256, 4)
void attn2(const unsigned short* __restrict__ qb,
           const unsigned short* __restrict__ kb,
           const unsigned short* __restrict__ vtb,
           unsigned short* __restrict__ ao) {
  __shared__ unsigned short kl[64][128];   // 16 KB : K tile (kpos x d), swizzled
  __shared__ unsigned short vl[128][64];   // 16 KB : V^T tile (d x kpos), swizzled

  const int tid = threadIdx.x;
  const int wave = tid >> 6, lane = tid & 63, quad = lane >> 4, lm = lane & 15;
  const int qblk = blockIdx.x & 15;
  const int bh = blockIdx.x >> 4;
  const int b = bh >> 4, h = bh & 15, kvh = h >> 2;
  const int q0 = qblk * 64 + wave * 16;

  // Q fragments (already scaled by SCALE_LOG2E at projection time)
  bf16x8 qf[4];
  const unsigned short* qbase = qb + ((size_t)((b * NH + h) * QL + q0)) * HD;
  #pragma unroll
  for (int kq = 0; kq < 4; ++kq)
    qf[kq] = *(const bf16x8*)(qbase + lm * HD + kq * 32 + quad * 8);

  f32x4 o[8];
  float li = 0.f;
  #pragma unroll
  for (int dt = 0; dt < 8; ++dt)
    #pragma unroll
    for (int rr = 0; rr < 4; ++rr) o[dt][rr] = 0.f;

  const unsigned short* kbase = kb + ((size_t)(b * NKV + kvh)) * KL * HD;
  const unsigned short* vbase = vtb + ((size_t)(b * NKV + kvh)) * HD * KL;

  const unsigned short* kgp[4];
  const unsigned short* vgp[4];
  #pragma unroll
  for (int i = 0; i < 4; ++i) {
    const int idx = i * 256 + tid;
    const int krow = idx >> 4, gc = idx & 15;
    const int gg = (gc & 8) | ((gc & 7) ^ (krow & 7));
    kgp[i] = kbase + (size_t)krow * HD + gg * 8;
    const int vrow = idx >> 3, g = idx & 7;
    const int gv = g ^ (vrow & 7);
    vgp[i] = vbase + (size_t)vrow * KL + gv * 8;
  }

  for (int kt = 0; kt < KL / 64; ++kt) {
    __syncthreads();
    #pragma unroll
    for (int i = 0; i < 4; ++i) {
      async16(kgp[i] + (size_t)kt * 64 * HD, (char*)&kl[0][0] + (i * 256 + wave * 64) * 16);
      async16(vgp[i] + kt * 64,              (char*)&vl[0][0] + (i * 256 + wave * 64) * 16);
    }
    __syncthreads();

    #pragma unroll
    for (int nt = 0; nt < 4; ++nt) {
      bf16x8 kf[4];
      #pragma unroll
      for (int kq = 0; kq < 4; ++kq) {
        const int gc = kq * 4 + quad;
        const int swz = (gc & 8) | ((gc & 7) ^ (lm & 7));
        kf[kq] = *(const bf16x8*)&kl[nt * 16 + lm][swz * 8];
      }
      f32x4 s0 = {0.f, 0.f, 0.f, 0.f};
      __builtin_amdgcn_s_setprio(1);
      #pragma unroll
      for (int kq = 0; kq < 4; ++kq)
        s0 = __builtin_amdgcn_mfma_f32_16x16x32_bf16(kf[kq], qf[kq], s0, 0, 0, 0);
      __builtin_amdgcn_s_setprio(0);
      float e00 = __builtin_amdgcn_exp2f(s0[0]), e01 = __builtin_amdgcn_exp2f(s0[1]);
      float e02 = __builtin_amdgcn_exp2f(s0[2]), e03 = __builtin_amdgcn_exp2f(s0[3]);
      li += (e00 + e01) + (e02 + e03);
      bf16x4 p0 = mk4(e00, e01, e02, e03);
      __builtin_amdgcn_s_setprio(1);
      #pragma unroll
      for (int dt = 0; dt < 8; ++dt) {
        const int gv = (nt * 2 + (quad >> 1)) ^ (lm & 7);
        bf16x4 vf = *(const bf16x4*)&vl[dt * 16 + lm][gv * 8 + (quad & 1) * 4];
        o[dt] = __builtin_amdgcn_mfma_f32_16x16x16bf16_1k(vf, p0, o[dt], 0, 0, 0);
      }
      __builtin_amdgcn_s_setprio(0);
    }
  }

  {
    float l = li;
    l += __shfl_xor(l, 16);
    l += __shfl_xor(l, 32);
    const float inv = 1.0f / l;
    const size_t rowbase = ((size_t)(b * QL + q0 + lm)) * (NH * HD) + h * HD;
    #pragma unroll
    for (int dt = 0; dt < 8; ++dt) {
      bf16x4 v = mk4(o[dt][0] * inv, o[dt][1] * inv,
                     o[dt][2] * inv, o[dt][3] * inv);
      *(bf16x4*)(ao + rowbase + dt * 16 + quad * 4) = v;
    }
  }
}

// ---------------------------------------------------------------------------
extern "C" void kernel_launch(void* const* d_in, const int* in_sizes, int n_in,
                              void* d_out, int out_size, void* d_ws, size_t ws_size,
                              hipStream_t stream) {
  const float* noise = (const float*)d_in[0];
  const float* ctx   = (const float*)d_in[1];
  const float* cosb  = (const float*)d_in[2];
  const float* sinb  = (const float*)d_in[3];
  const float* Wq    = (const float*)d_in[4];
  const float* Wk    = (const float*)d_in[5];
  const float* Wv    = (const float*)d_in[6];
  const float* Wo    = (const float*)d_in[7];
  const float* qn    = (const float*)d_in[8];
  const float* kn    = (const float*)d_in[9];
  float* out = (float*)d_out;

  char* ws = (char*)d_ws;
  // kvin: 64 MB [0,64M).  aob aliases kvin[0:16M) (kvin dead after V-proj).
  unsigned short* kvin = (unsigned short*)(ws);
  unsigned short* aob  = (unsigned short*)(ws);
  unsigned short* WqT  = (unsigned short*)(ws + 67108864);            //  8 MB
  unsigned short* WkT  = (unsigned short*)(ws + 67108864 + 8388608);  //  2 MB
  unsigned short* WvT  = (unsigned short*)(ws + 67108864 + 10485760); //  2 MB
  unsigned short* WoT  = (unsigned short*)(ws + 67108864 + 12582912); //  8 MB
  unsigned short* qbuf = (unsigned short*)(ws + 67108864 + 20971520); // 16 MB
  unsigned short* kbuf = (unsigned short*)(ws + 67108864 + 37748736); // 16 MB
  unsigned short* vtb  = (unsigned short*)(ws + 67108864 + 54525952); // 16 MB (total 132 MB)

  prep<<<dim3((B_ * KL * H_) / 8 / 256), dim3(256), 0, stream>>>(noise, ctx, kvin);

  wtrans<<<dim3(1024), dim3(256), 0, stream>>>(Wq, WqT, 2048, 2048);
  wtrans<<<dim3(256),  dim3(256), 0, stream>>>(Wk, WkT, 2048, 512);
  wtrans<<<dim3(256),  dim3(256), 0, stream>>>(Wv, WvT, 2048, 512);
  wtrans<<<dim3(1024), dim3(256), 0, stream>>>(Wo, WoT, 2048, 2048);

  gemm2<0><<<dim3(32 * 16), dim3(256), 0, stream>>>(
      kvin, WqT, qn, cosb, sinb, qbuf, nullptr);
  gemm2<1><<<dim3(128 * 4), dim3(256), 0, stream>>>(
      kvin, WkT, kn, cosb, sinb, kbuf, nullptr);
  gemm2<2><<<dim3(128 * 4), dim3(256), 0, stream>>>(
      kvin, WvT, nullptr, nullptr, nullptr, vtb, nullptr);

  attn2<<<dim3(1024), dim3(256), 0, stream>>>(qbuf, kbuf, vtb, aob);

  gemm2<3><<<dim3(32 * 16), dim3(256), 0, stream>>>(
      aob, WoT, nullptr, nullptr, nullptr, nullptr, out);
}

// Round 2
// 636.290 us; speedup vs baseline: 1.0031x; 1.0031x over previous
//
#include <hip/hip_runtime.h>
#include <cstdint>
#include <cstddef>

#define DEVI __device__ __forceinline__

typedef short bf16x8 __attribute__((ext_vector_type(8)));
typedef short bf16x4 __attribute__((ext_vector_type(4)));
typedef float f32x4  __attribute__((ext_vector_type(4)));

constexpr int H_  = 2048;
constexpr int NH  = 16;
constexpr int NKV = 4;
constexpr int HD  = 128;
constexpr int B_  = 4;
constexpr int QL  = 1024;
constexpr int CL  = 3072;
constexpr int KL  = 4096;   // CL + QL
constexpr float EPS = 1e-6f;
// SCALE * log2(e): folded into stored Q so attention softmax is bare exp2
constexpr float SCALE_LOG2E = 0.08838834764831845f * 1.4426950408889634f;

DEVI unsigned short f2bf(float x) {
  unsigned int u = __float_as_uint(x);
  u += 0x7FFFu + ((u >> 16) & 1u);   // RNE
  return (unsigned short)(u >> 16);
}
DEVI float bf2f(unsigned short u) {
  return __uint_as_float(((unsigned int)u) << 16);
}
// pack 4 fp32 -> 4 bf16 with round-half-up (cheap: add + v_perm)
DEVI bf16x4 mk4(float a, float b, float c, float d) {
  unsigned ua = __float_as_uint(a) + 0x8000u, ub = __float_as_uint(b) + 0x8000u;
  unsigned uc = __float_as_uint(c) + 0x8000u, ud = __float_as_uint(d) + 0x8000u;
  union { unsigned u[2]; bf16x4 v; } r;
  r.u[0] = __builtin_amdgcn_perm(ub, ua, 0x07060302u);  // hi16(b):hi16(a)
  r.u[1] = __builtin_amdgcn_perm(ud, uc, 0x07060302u);
  return r.v;
}

DEVI void async16(const void* g, void* l) {
  __builtin_amdgcn_global_load_lds(
      (const __attribute__((address_space(1))) void*)g,
      (__attribute__((address_space(3))) void*)l, 16, 0, 0);
}

// ---------------------------------------------------------------------------
// prep: kvin_bf[b][pos][h] = bf16(concat(ctx, noise))   (b, KL, H)
// ---------------------------------------------------------------------------
__global__ __launch_bounds__(256)
void prep(const float* __restrict__ noise, const float* __restrict__ ctx,
          unsigned short* __restrict__ kvin) {
  const size_t t = (size_t)blockIdx.x * 256 + threadIdx.x;   // one 8-elem chunk
  const size_t e = t * 8;
  const int row = (int)(e / H_), col = (int)(e % H_);
  const int b = row >> 12, pos = row & 4095;
  const float* src = (pos < CL) ? ctx + ((size_t)(b * CL + pos)) * H_ + col
                                : noise + ((size_t)(b * QL + (pos - CL))) * H_ + col;
  float4 x = ((const float4*)src)[0], y = ((const float4*)src)[1];
  bf16x8 v;
  v[0] = (short)f2bf(x.x); v[1] = (short)f2bf(x.y);
  v[2] = (short)f2bf(x.z); v[3] = (short)f2bf(x.w);
  v[4] = (short)f2bf(y.x); v[5] = (short)f2bf(y.y);
  v[6] = (short)f2bf(y.z); v[7] = (short)f2bf(y.w);
  *(bf16x8*)(kvin + e) = v;
}

// ---------------------------------------------------------------------------
// Weight transpose + fp32 -> bf16:  in (K x N) fp32  ->  out (N x K) bf16
// ---------------------------------------------------------------------------
__global__ __launch_bounds__(256)
void wtrans(const float* __restrict__ in, unsigned short* __restrict__ out,
            int K, int N) {
  __shared__ float t[64][65];
  const int ktiles = K >> 6;
  const int kt = blockIdx.x % ktiles;
  const int nt = blockIdx.x / ktiles;
  {
    const int r = threadIdx.x >> 2, cs = threadIdx.x & 3;
    const float4* src = (const float4*)(in + (size_t)(kt * 64 + r) * N + nt * 64 + cs * 16);
    #pragma unroll
    for (int i = 0; i < 4; ++i) {
      float4 v = src[i];
      t[r][cs * 16 + i * 4 + 0] = v.x;
      t[r][cs * 16 + i * 4 + 1] = v.y;
      t[r][cs * 16 + i * 4 + 2] = v.z;
      t[r][cs * 16 + i * 4 + 3] = v.w;
    }
  }
  __syncthreads();
  {
    const int n = threadIdx.x >> 2, ks = threadIdx.x & 3;
    bf16x8 o0, o1;
    #pragma unroll
    for (int i = 0; i < 8; ++i) o0[i] = (short)f2bf(t[ks * 16 + i][n]);
    #pragma unroll
    for (int i = 0; i < 8; ++i) o1[i] = (short)f2bf(t[ks * 16 + 8 + i][n]);
    unsigned short* op = out + (size_t)(nt * 64 + n) * K + kt * 64 + ks * 16;
    *(bf16x8*)(op) = o0;
    *(bf16x8*)(op + 8) = o1;
  }
}

// ---------------------------------------------------------------------------
// m97-style GEMM, both operands bf16 via global_load_lds w/ XOR granule swizzle.
// C(M x N) = A(M x 2048) @ B(2048 x N), B given transposed (N x K) bf16.
// MODE 0: A=kvin rows (b,CL+q)  -> rmsnorm+rope, *SCALE_LOG2E -> q  (b,h,q,d)
// MODE 1: A=kvin                -> rmsnorm+rope -> k  (b,kv,p,d)
// MODE 2: A=kvin                -> transpose    -> vT (b,kv,d,p)
// MODE 3: A=attn_out bf16       -> fp32 d_out
// ---------------------------------------------------------------------------
template <int MODE>
__global__ __launch_bounds__(256)
void gemm2(const unsigned short* __restrict__ Abf,
           const unsigned short* __restrict__ Bt,
           const float* __restrict__ normw,
           const float* __restrict__ cosb, const float* __restrict__ sinb,
           unsigned short* __restrict__ outb, float* __restrict__ outf) {
  constexpr int M  = (MODE == 1 || MODE == 2) ? (B_ * KL) : (B_ * QL);
  constexpr int K  = H_;
  constexpr int MT = M / 128;

  __shared__ union U {
    struct { unsigned short a[128][64]; unsigned short b[128][64]; } st; // 32 KB
    unsigned short ct[128][138];                                         // 35.3 KB
  } sm;

  const int tid  = threadIdx.x;
  const int tm   = blockIdx.x % MT;
  const int tn   = blockIdx.x / MT;
  const int wid  = tid >> 6, lane = tid & 63, quad = lane >> 4, lm = lane & 15;
  const int wm   = wid >> 1, wn = wid & 1;

  f32x4 acc[4][4];
  #pragma unroll
  for (int i = 0; i < 4; ++i)
    #pragma unroll
    for (int j = 0; j < 4; ++j)
      #pragma unroll
      for (int r = 0; r < 4; ++r) acc[i][j][r] = 0.f;

  // staging pointers (per 16B granule; LDS side is linear: offset 16*idx)
  const unsigned short* agp[4];
  const unsigned short* bgp[4];
  #pragma unroll
  for (int i = 0; i < 4; ++i) {
    const int idx = i * 256 + tid;
    const int arow = idx >> 3, g = idx & 7, gg = g ^ (arow & 7);
    int grow;
    if constexpr (MODE == 0) {
      const int gmr = tm * 128 + arow;
      grow = (gmr >> 10) * KL + CL + (gmr & 1023);
    } else {
      grow = tm * 128 + arow;
    }
    agp[i] = Abf + (size_t)grow * K + gg * 8;
    bgp[i] = Bt + (size_t)(tn * 128 + arow) * K + gg * 8;
  }

  for (int kt = 0; kt < K / 64; ++kt) {
    __syncthreads();
    #pragma unroll
    for (int i = 0; i < 4; ++i) {
      async16(agp[i] + kt * 64, (char*)&sm.st.a[0][0] + (i * 256 + wid * 64) * 16);
      async16(bgp[i] + kt * 64, (char*)&sm.st.b[0][0] + (i * 256 + wid * 64) * 16);
    }
    __syncthreads();
    #pragma unroll
    for (int ks = 0; ks < 2; ++ks) {
      bf16x8 af[4], bfr[4];
      #pragma unroll
      for (int i = 0; i < 4; ++i) {
        const int swz = (ks * 4 + quad) ^ (lm & 7);
        af[i] = *(const bf16x8*)&sm.st.a[wm * 64 + i * 16 + lm][swz * 8];
      }
      #pragma unroll
      for (int j = 0; j < 4; ++j) {
        const int swz = (ks * 4 + quad) ^ (lm & 7);
        bfr[j] = *(const bf16x8*)&sm.st.b[wn * 64 + j * 16 + lm][swz * 8];
      }
      #pragma unroll
      for (int i = 0; i < 4; ++i)
        #pragma unroll
        for (int j = 0; j < 4; ++j)
          acc[i][j] = __builtin_amdgcn_mfma_f32_16x16x32_bf16(af[i], bfr[j], acc[i][j], 0, 0, 0);
    }
  }

  if constexpr (MODE == 3) {
    #pragma unroll
    for (int i = 0; i < 4; ++i)
      #pragma unroll
      for (int j = 0; j < 4; ++j) {
        const int row = tm * 128 + wm * 64 + i * 16 + quad * 4;
        const int col = tn * 128 + wn * 64 + j * 16 + lm;
        #pragma unroll
        for (int rr = 0; rr < 4; ++rr)
          outf[(size_t)(row + rr) * H_ + col] = acc[i][j][rr];
      }
    return;
  }

  // C tile -> LDS bf16
  __syncthreads();
  #pragma unroll
  for (int i = 0; i < 4; ++i)
    #pragma unroll
    for (int j = 0; j < 4; ++j)
      #pragma unroll
      for (int rr = 0; rr < 4; ++rr)
        sm.ct[wm * 64 + i * 16 + quad * 4 + rr][wn * 64 + j * 16 + lm] =
            f2bf(acc[i][j][rr]);
  __syncthreads();

  const int row2 = tid >> 1, half = tid & 1;
  if constexpr (MODE == 0 || MODE == 1) {
    const int gmr = tm * 128 + row2;
    int ci; size_t obase;
    if constexpr (MODE == 0) {
      const int b = gmr >> 10, pos = gmr & 1023;
      ci = (b * KL + CL + pos) * HD;
      obase = ((size_t)((b * NH + tn) * QL + pos)) * HD;
    } else {
      const int b = gmr >> 12, pos = gmr & 4095;
      ci = (b * KL + pos) * HD;
      obase = ((size_t)((b * NKV + tn) * KL + pos)) * HD;
    }
    float ss = 0.f;
    for (int d = half * 64; d < half * 64 + 64; ++d) {
      float v = bf2f(sm.ct[row2][d]);
      ss += v * v;
    }
    ss += __shfl_xor(ss, 1);
    const float rinv = rsqrtf(ss * (1.0f / 128.0f) + EPS);
    constexpr float OSC = (MODE == 0) ? SCALE_LOG2E : 1.0f;
    #pragma unroll
    for (int d8 = 0; d8 < 8; ++d8) {
      bf16x8 v;
      #pragma unroll
      for (int j = 0; j < 8; ++j) {
        const int d = half * 64 + d8 * 8 + j;
        const float x  = bf2f(sm.ct[row2][d])      * rinv * normw[d];
        const float xo = bf2f(sm.ct[row2][d ^ 64]) * rinv * normw[d ^ 64];
        const float rot = (d < 64) ? -xo : xo;
        v[j] = (short)f2bf((x * cosb[ci + d] + rot * sinb[ci + d]) * OSC);
      }
      *(bf16x8*)(outb + obase + half * 64 + d8 * 8) = v;
    }
  } else {
    // MODE 2: V^T  (b, kv, d, pos)
    const int d = row2;
    const int b = (tm * 128) >> 12;
    const int posBase = ((tm * 128) & 4095) + half * 64;
    const size_t obase = ((size_t)((b * NKV + tn) * HD + d)) * KL + posBase;
    #pragma unroll
    for (int k8 = 0; k8 < 8; ++k8) {
      bf16x8 v;
      #pragma unroll
      for (int j = 0; j < 8; ++j)
        v[j] = (short)sm.ct[half * 64 + k8 * 8 + j][d];
      *(bf16x8*)(outb + obase + k8 * 8) = v;
    }
  }
}

// ---------------------------------------------------------------------------
// Flash attention v3.  Block = one (b,h) x 256 q rows; 4 waves x 64 q rows
// (W=4 q-tiles per wave).  Grid = 64 bh x 4 qblk = 256 blocks = 1 block/CU.
// Round-1 lesson: LDS-read traffic = (q-tiles/W) x iters x 32KB -- each wave
// reads the FULL K/V tile regardless of W.  W=4 quarters LDS reads vs W=1
// (8.6GB -> 2.1GB) and gives 4 independent MFMA chains for in-wave ILP, so
// 1 wave/SIMD suffices.  Double-buffered LDS + counted vmcnt(8) + raw
// s_barrier (T3/T4 minimal 2-phase): next tile's 8 global_load_lds stay in
// flight across the barrier; staging latency hides under ~1300cy of compute.
// S^T = K Q^T (16x16x32) -> p = exp2(s) in regs -> O^T += V^T P^T (16x16x16,
// P^T direct from S^T's C-layout regs).  No-max softmax (|s|<=16.3 in exp2
// domain, bounded by RMSNorm), li reduced once at end.
// ---------------------------------------------------------------------------
__global__ __launch_bounds__(256, 1)
void attn2(const unsigned short* __restrict__ qb,
           const unsigned short* __restrict__ kb,
           const unsigned short* __restrict__ vtb,
           unsigned short* __restrict__ ao) {
  __shared__ unsigned short kl[2][64][128];   // 2 x 16 KB : K tile (kpos x d)
  __shared__ unsigned short vl[2][128][64];   // 2 x 16 KB : V^T tile (d x kpos)

  const int tid = threadIdx.x;
  const int wave = tid >> 6, lane = tid & 63, quad = lane >> 4, lm = lane & 15;
  const int qblk = blockIdx.x & 3;
  const int bh = blockIdx.x >> 2;
  const int b = bh >> 4, h = bh & 15, kvh = h >> 2;
  const int q0 = qblk * 256 + wave * 64;   // this wave's 64 q rows (4 tiles)

  // Q fragments (already scaled by SCALE_LOG2E at projection time)
  bf16x8 qf[4][4];
  const unsigned short* qbase = qb + ((size_t)((b * NH + h) * QL + q0)) * HD;
  #pragma unroll
  for (int t = 0; t < 4; ++t)
    #pragma unroll
    for (int kq = 0; kq < 4; ++kq)
      qf[t][kq] = *(const bf16x8*)(qbase + (t * 16 + lm) * HD + kq * 32 + quad * 8);

  f32x4 o[4][8];
  float li[4] = {0.f, 0.f, 0.f, 0.f};
  #pragma unroll
  for (int t = 0; t < 4; ++t)
    #pragma unroll
    for (int dt = 0; dt < 8; ++dt)
      #pragma unroll
      for (int rr = 0; rr < 4; ++rr) o[t][dt][rr] = 0.f;

  const unsigned short* kbase = kb + ((size_t)(b * NKV + kvh)) * KL * HD;
  const unsigned short* vbase = vtb + ((size_t)(b * NKV + kvh)) * HD * KL;

  // per-thread staging granule (XOR swizzle identical to r0; granule i at
  // fixed XOR because row advances by multiples of 8 across i)
  const int krow0 = tid >> 4, kgc = tid & 15;
  const int kgg = (kgc & 8) | ((kgc & 7) ^ (krow0 & 7));
  const unsigned short* kgp0 = kbase + (size_t)krow0 * HD + kgg * 8;
  const int vrow0 = tid >> 3;
  const int vgv = (tid & 7) ^ (vrow0 & 7);
  const unsigned short* vgp0 = vbase + (size_t)vrow0 * KL + vgv * 8;

  auto stage = [&](int bufi, int ktt) {
    #pragma unroll
    for (int i = 0; i < 4; ++i) {
      async16(kgp0 + (size_t)ktt * (64 * HD) + i * (16 * HD),
              (char*)&kl[bufi][0][0] + (i * 256 + wave * 64) * 16);
      async16(vgp0 + (size_t)ktt * 64 + i * (32 * KL),
              (char*)&vl[bufi][0][0] + (i * 256 + wave * 64) * 16);
    }
  };

  stage(0, 0);
  for (int kt = 0; kt < KL / 64; ++kt) {
    const int cur = kt & 1;
    if (kt + 1 < KL / 64) {
      stage(cur ^ 1, kt + 1);                       // 8 loads in flight
      asm volatile("s_waitcnt vmcnt(8)" ::: "memory");   // wait only cur's 8
    } else {
      asm volatile("s_waitcnt vmcnt(0)" ::: "memory");
    }
    __builtin_amdgcn_s_barrier();

    #pragma unroll
    for (int nt = 0; nt < 4; ++nt) {
      bf16x8 kf[4];
      #pragma unroll
      for (int kq = 0; kq < 4; ++kq) {
        const int gc = kq * 4 + quad;
        const int swz = (gc & 8) | ((gc & 7) ^ (lm & 7));
        kf[kq] = *(const bf16x8*)&kl[cur][nt * 16 + lm][swz * 8];
      }
      bf16x4 vf[8];
      #pragma unroll
      for (int dt = 0; dt < 8; ++dt) {
        const int gv = (nt * 2 + (quad >> 1)) ^ (lm & 7);
        vf[dt] = *(const bf16x4*)&vl[cur][dt * 16 + lm][gv * 8 + (quad & 1) * 4];
      }
      f32x4 s[4];
      #pragma unroll
      for (int t = 0; t < 4; ++t)
        #pragma unroll
        for (int rr = 0; rr < 4; ++rr) s[t][rr] = 0.f;
      #pragma unroll
      for (int kq = 0; kq < 4; ++kq)
        #pragma unroll
        for (int t = 0; t < 4; ++t)
          s[t] = __builtin_amdgcn_mfma_f32_16x16x32_bf16(kf[kq], qf[t][kq], s[t], 0, 0, 0);
      // t-outer so exp2(t+1) overlaps PV(t) MFMAs
      #pragma unroll
      for (int t = 0; t < 4; ++t) {
        float e0 = __builtin_amdgcn_exp2f(s[t][0]);
        float e1 = __builtin_amdgcn_exp2f(s[t][1]);
        float e2 = __builtin_amdgcn_exp2f(s[t][2]);
        float e3 = __builtin_amdgcn_exp2f(s[t][3]);
        li[t] += (e0 + e1) + (e2 + e3);
        bf16x4 p = mk4(e0, e1, e2, e3);
        #pragma unroll
        for (int dt = 0; dt < 8; ++dt)
          o[t][dt] = __builtin_amdgcn_mfma_f32_16x16x16bf16_1k(vf[dt], p, o[t][dt], 0, 0, 0);
      }
    }
    __builtin_amdgcn_s_barrier();
  }

  #pragma unroll
  for (int t = 0; t < 4; ++t) {
    float l = li[t];
    l += __shfl_xor(l, 16);
    l += __shfl_xor(l, 32);
    const float inv = 1.0f / l;
    const size_t rowbase = ((size_t)(b * QL + q0 + t * 16 + lm)) * (NH * HD) + h * HD;
    #pragma unroll
    for (int dt = 0; dt < 8; ++dt) {
      bf16x4 v = mk4(o[t][dt][0] * inv, o[t][dt][1] * inv,
                     o[t][dt][2] * inv, o[t][dt][3] * inv);
      *(bf16x4*)(ao + rowbase + dt * 16 + quad * 4) = v;
    }
  }
}

// ---------------------------------------------------------------------------
extern "C" void kernel_launch(void* const* d_in, const int* in_sizes, int n_in,
                              void* d_out, int out_size, void* d_ws, size_t ws_size,
                              hipStream_t stream) {
  const float* noise = (const float*)d_in[0];
  const float* ctx   = (const float*)d_in[1];
  const float* cosb  = (const float*)d_in[2];
  const float* sinb  = (const float*)d_in[3];
  const float* Wq    = (const float*)d_in[4];
  const float* Wk    = (const float*)d_in[5];
  const float* Wv    = (const float*)d_in[6];
  const float* Wo    = (const float*)d_in[7];
  const float* qn    = (const float*)d_in[8];
  const float* kn    = (const float*)d_in[9];
  float* out = (float*)d_out;

  char* ws = (char*)d_ws;
  // kvin: 64 MB [0,64M).  aob aliases kvin[0:16M) (kvin dead after V-proj).
  unsigned short* kvin = (unsigned short*)(ws);
  unsigned short* aob  = (unsigned short*)(ws);
  unsigned short* WqT  = (unsigned short*)(ws + 67108864);            //  8 MB
  unsigned short* WkT  = (unsigned short*)(ws + 67108864 + 8388608);  //  2 MB
  unsigned short* WvT  = (unsigned short*)(ws + 67108864 + 10485760); //  2 MB
  unsigned short* WoT  = (unsigned short*)(ws + 67108864 + 12582912); //  8 MB
  unsigned short* qbuf = (unsigned short*)(ws + 67108864 + 20971520); // 16 MB
  unsigned short* kbuf = (unsigned short*)(ws + 67108864 + 37748736); // 16 MB
  unsigned short* vtb  = (unsigned short*)(ws + 67108864 + 54525952); // 16 MB (total 132 MB)

  prep<<<dim3((B_ * KL * H_) / 8 / 256), dim3(256), 0, stream>>>(noise, ctx, kvin);

  wtrans<<<dim3(1024), dim3(256), 0, stream>>>(Wq, WqT, 2048, 2048);
  wtrans<<<dim3(256),  dim3(256), 0, stream>>>(Wk, WkT, 2048, 512);
  wtrans<<<dim3(256),  dim3(256), 0, stream>>>(Wv, WvT, 2048, 512);
  wtrans<<<dim3(1024), dim3(256), 0, stream>>>(Wo, WoT, 2048, 2048);

  gemm2<0><<<dim3(32 * 16), dim3(256), 0, stream>>>(
      kvin, WqT, qn, cosb, sinb, qbuf, nullptr);
  gemm2<1><<<dim3(128 * 4), dim3(256), 0, stream>>>(
      kvin, WkT, kn, cosb, sinb, kbuf, nullptr);
  gemm2<2><<<dim3(128 * 4), dim3(256), 0, stream>>>(
      kvin, WvT, nullptr, nullptr, nullptr, vtb, nullptr);

  attn2<<<dim3(256), dim3(256), 0, stream>>>(qbuf, kbuf, vtb, aob);

  gemm2<3><<<dim3(32 * 16), dim3(256), 0, stream>>>(
      aob, WoT, nullptr, nullptr, nullptr, nullptr, out);
}

// Round 3
// 584.308 us; speedup vs baseline: 1.0923x; 1.0890x over previous
//
#include <hip/hip_runtime.h>
#include <cstdint>
#include <cstddef>

#define DEVI __device__ __forceinline__

typedef short bf16x8 __attribute__((ext_vector_type(8)));
typedef short bf16x4 __attribute__((ext_vector_type(4)));
typedef float f32x4  __attribute__((ext_vector_type(4)));

constexpr int H_  = 2048;
constexpr int NH  = 16;
constexpr int NKV = 4;
constexpr int HD  = 128;
constexpr int B_  = 4;
constexpr int QL  = 1024;
constexpr int CL  = 3072;
constexpr int KL  = 4096;   // CL + QL
constexpr float EPS = 1e-6f;
// SCALE * log2(e): folded into stored Q so attention softmax is bare exp2
constexpr float SCALE_LOG2E = 0.08838834764831845f * 1.4426950408889634f;

DEVI unsigned short f2bf(float x) {
  unsigned int u = __float_as_uint(x);
  u += 0x7FFFu + ((u >> 16) & 1u);   // RNE
  return (unsigned short)(u >> 16);
}
DEVI float bf2f(unsigned short u) {
  return __uint_as_float(((unsigned int)u) << 16);
}
// pack 2 fp32 -> u32 of 2 bf16 (round-half-up: add + v_perm)
DEVI unsigned mk2(float a, float b) {
  unsigned ua = __float_as_uint(a) + 0x8000u, ub = __float_as_uint(b) + 0x8000u;
  return __builtin_amdgcn_perm(ub, ua, 0x07060302u);  // hi16(b):hi16(a)
}
// pack 4 fp32 -> 4 bf16
DEVI bf16x4 mk4(float a, float b, float c, float d) {
  union { unsigned u[2]; bf16x4 v; } r;
  r.u[0] = mk2(a, b);
  r.u[1] = mk2(c, d);
  return r.v;
}

DEVI void async16(const void* g, void* l) {
  __builtin_amdgcn_global_load_lds(
      (const __attribute__((address_space(1))) void*)g,
      (__attribute__((address_space(3))) void*)l, 16, 0, 0);
}

// ---------------------------------------------------------------------------
// prep: kvin_bf[b][pos][h] = bf16(concat(ctx, noise))   (b, KL, H)
// ---------------------------------------------------------------------------
__global__ __launch_bounds__(256)
void prep(const float* __restrict__ noise, const float* __restrict__ ctx,
          unsigned short* __restrict__ kvin) {
  const size_t t = (size_t)blockIdx.x * 256 + threadIdx.x;   // one 8-elem chunk
  const size_t e = t * 8;
  const int row = (int)(e / H_), col = (int)(e % H_);
  const int b = row >> 12, pos = row & 4095;
  const float* src = (pos < CL) ? ctx + ((size_t)(b * CL + pos)) * H_ + col
                                : noise + ((size_t)(b * QL + (pos - CL))) * H_ + col;
  float4 x = ((const float4*)src)[0], y = ((const float4*)src)[1];
  bf16x8 v;
  v[0] = (short)f2bf(x.x); v[1] = (short)f2bf(x.y);
  v[2] = (short)f2bf(x.z); v[3] = (short)f2bf(x.w);
  v[4] = (short)f2bf(y.x); v[5] = (short)f2bf(y.y);
  v[6] = (short)f2bf(y.z); v[7] = (short)f2bf(y.w);
  *(bf16x8*)(kvin + e) = v;
}

// ---------------------------------------------------------------------------
// Weight transpose + fp32 -> bf16:  in (K x N) fp32  ->  out (N x K) bf16
// ---------------------------------------------------------------------------
__global__ __launch_bounds__(256)
void wtrans(const float* __restrict__ in, unsigned short* __restrict__ out,
            int K, int N) {
  __shared__ float t[64][65];
  const int ktiles = K >> 6;
  const int kt = blockIdx.x % ktiles;
  const int nt = blockIdx.x / ktiles;
  {
    const int r = threadIdx.x >> 2, cs = threadIdx.x & 3;
    const float4* src = (const float4*)(in + (size_t)(kt * 64 + r) * N + nt * 64 + cs * 16);
    #pragma unroll
    for (int i = 0; i < 4; ++i) {
      float4 v = src[i];
      t[r][cs * 16 + i * 4 + 0] = v.x;
      t[r][cs * 16 + i * 4 + 1] = v.y;
      t[r][cs * 16 + i * 4 + 2] = v.z;
      t[r][cs * 16 + i * 4 + 3] = v.w;
    }
  }
  __syncthreads();
  {
    const int n = threadIdx.x >> 2, ks = threadIdx.x & 3;
    bf16x8 o0, o1;
    #pragma unroll
    for (int i = 0; i < 8; ++i) o0[i] = (short)f2bf(t[ks * 16 + i][n]);
    #pragma unroll
    for (int i = 0; i < 8; ++i) o1[i] = (short)f2bf(t[ks * 16 + 8 + i][n]);
    unsigned short* op = out + (size_t)(nt * 64 + n) * K + kt * 64 + ks * 16;
    *(bf16x8*)(op) = o0;
    *(bf16x8*)(op + 8) = o1;
  }
}

// ---------------------------------------------------------------------------
// m97-style GEMM, both operands bf16 via global_load_lds w/ XOR granule swizzle.
// C(M x N) = A(M x 2048) @ B(2048 x N), B given transposed (N x K) bf16.
// MODE 0: A=kvin rows (b,CL+q)  -> rmsnorm+rope, *SCALE_LOG2E -> q  (b,h,q,d)
// MODE 1: A=kvin                -> rmsnorm+rope -> k  (b,kv,p,d)
// MODE 2: A=kvin                -> transpose    -> vT (b,kv,d,p)
// MODE 3: A=attn_out bf16       -> fp32 d_out
// ---------------------------------------------------------------------------
template <int MODE>
__global__ __launch_bounds__(256)
void gemm2(const unsigned short* __restrict__ Abf,
           const unsigned short* __restrict__ Bt,
           const float* __restrict__ normw,
           const float* __restrict__ cosb, const float* __restrict__ sinb,
           unsigned short* __restrict__ outb, float* __restrict__ outf) {
  constexpr int M  = (MODE == 1 || MODE == 2) ? (B_ * KL) : (B_ * QL);
  constexpr int K  = H_;
  constexpr int MT = M / 128;

  __shared__ union U {
    struct { unsigned short a[128][64]; unsigned short b[128][64]; } st; // 32 KB
    unsigned short ct[128][138];                                         // 35.3 KB
  } sm;

  const int tid  = threadIdx.x;
  const int tm   = blockIdx.x % MT;
  const int tn   = blockIdx.x / MT;
  const int wid  = tid >> 6, lane = tid & 63, quad = lane >> 4, lm = lane & 15;
  const int wm   = wid >> 1, wn = wid & 1;

  f32x4 acc[4][4];
  #pragma unroll
  for (int i = 0; i < 4; ++i)
    #pragma unroll
    for (int j = 0; j < 4; ++j)
      #pragma unroll
      for (int r = 0; r < 4; ++r) acc[i][j][r] = 0.f;

  // staging pointers (per 16B granule; LDS side is linear: offset 16*idx)
  const unsigned short* agp[4];
  const unsigned short* bgp[4];
  #pragma unroll
  for (int i = 0; i < 4; ++i) {
    const int idx = i * 256 + tid;
    const int arow = idx >> 3, g = idx & 7, gg = g ^ (arow & 7);
    int grow;
    if constexpr (MODE == 0) {
      const int gmr = tm * 128 + arow;
      grow = (gmr >> 10) * KL + CL + (gmr & 1023);
    } else {
      grow = tm * 128 + arow;
    }
    agp[i] = Abf + (size_t)grow * K + gg * 8;
    bgp[i] = Bt + (size_t)(tn * 128 + arow) * K + gg * 8;
  }

  for (int kt = 0; kt < K / 64; ++kt) {
    __syncthreads();
    #pragma unroll
    for (int i = 0; i < 4; ++i) {
      async16(agp[i] + kt * 64, (char*)&sm.st.a[0][0] + (i * 256 + wid * 64) * 16);
      async16(bgp[i] + kt * 64, (char*)&sm.st.b[0][0] + (i * 256 + wid * 64) * 16);
    }
    __syncthreads();
    #pragma unroll
    for (int ks = 0; ks < 2; ++ks) {
      bf16x8 af[4], bfr[4];
      #pragma unroll
      for (int i = 0; i < 4; ++i) {
        const int swz = (ks * 4 + quad) ^ (lm & 7);
        af[i] = *(const bf16x8*)&sm.st.a[wm * 64 + i * 16 + lm][swz * 8];
      }
      #pragma unroll
      for (int j = 0; j < 4; ++j) {
        const int swz = (ks * 4 + quad) ^ (lm & 7);
        bfr[j] = *(const bf16x8*)&sm.st.b[wn * 64 + j * 16 + lm][swz * 8];
      }
      #pragma unroll
      for (int i = 0; i < 4; ++i)
        #pragma unroll
        for (int j = 0; j < 4; ++j)
          acc[i][j] = __builtin_amdgcn_mfma_f32_16x16x32_bf16(af[i], bfr[j], acc[i][j], 0, 0, 0);
    }
  }

  if constexpr (MODE == 3) {
    #pragma unroll
    for (int i = 0; i < 4; ++i)
      #pragma unroll
      for (int j = 0; j < 4; ++j) {
        const int row = tm * 128 + wm * 64 + i * 16 + quad * 4;
        const int col = tn * 128 + wn * 64 + j * 16 + lm;
        #pragma unroll
        for (int rr = 0; rr < 4; ++rr)
          outf[(size_t)(row + rr) * H_ + col] = acc[i][j][rr];
      }
    return;
  }

  // C tile -> LDS bf16
  __syncthreads();
  #pragma unroll
  for (int i = 0; i < 4; ++i)
    #pragma unroll
    for (int j = 0; j < 4; ++j)
      #pragma unroll
      for (int rr = 0; rr < 4; ++rr)
        sm.ct[wm * 64 + i * 16 + quad * 4 + rr][wn * 64 + j * 16 + lm] =
            f2bf(acc[i][j][rr]);
  __syncthreads();

  const int row2 = tid >> 1, half = tid & 1;
  if constexpr (MODE == 0 || MODE == 1) {
    const int gmr = tm * 128 + row2;
    int ci; size_t obase;
    if constexpr (MODE == 0) {
      const int b = gmr >> 10, pos = gmr & 1023;
      ci = (b * KL + CL + pos) * HD;
      obase = ((size_t)((b * NH + tn) * QL + pos)) * HD;
    } else {
      const int b = gmr >> 12, pos = gmr & 4095;
      ci = (b * KL + pos) * HD;
      obase = ((size_t)((b * NKV + tn) * KL + pos)) * HD;
    }
    float ss = 0.f;
    for (int d = half * 64; d < half * 64 + 64; ++d) {
      float v = bf2f(sm.ct[row2][d]);
      ss += v * v;
    }
    ss += __shfl_xor(ss, 1);
    const float rinv = rsqrtf(ss * (1.0f / 128.0f) + EPS);
    constexpr float OSC = (MODE == 0) ? SCALE_LOG2E : 1.0f;
    #pragma unroll
    for (int d8 = 0; d8 < 8; ++d8) {
      bf16x8 v;
      #pragma unroll
      for (int j = 0; j < 8; ++j) {
        const int d = half * 64 + d8 * 8 + j;
        const float x  = bf2f(sm.ct[row2][d])      * rinv * normw[d];
        const float xo = bf2f(sm.ct[row2][d ^ 64]) * rinv * normw[d ^ 64];
        const float rot = (d < 64) ? -xo : xo;
        v[j] = (short)f2bf((x * cosb[ci + d] + rot * sinb[ci + d]) * OSC);
      }
      *(bf16x8*)(outb + obase + half * 64 + d8 * 8) = v;
    }
  } else {
    // MODE 2: V^T  (b, kv, d, pos)
    const int d = row2;
    const int b = (tm * 128) >> 12;
    const int posBase = ((tm * 128) & 4095) + half * 64;
    const size_t obase = ((size_t)((b * NKV + tn) * HD + d)) * KL + posBase;
    #pragma unroll
    for (int k8 = 0; k8 < 8; ++k8) {
      bf16x8 v;
      #pragma unroll
      for (int j = 0; j < 8; ++j)
        v[j] = (short)sm.ct[half * 64 + k8 * 8 + j][d];
      *(bf16x8*)(outb + obase + k8 * 8) = v;
    }
  }
}

// ---------------------------------------------------------------------------
// Flash attention v4.  r0 tiling (best measured): block = (b,h) x 128 q rows,
// 4 waves x 32 q (W=2 16-row tiles); grid 512 = 2 blocks/CU, 2 waves/SIMD.
// Lesson r1/r2: MfmaUtil+VALUBusy ~= 100% every round -> time = SUM of pipe
// times (in-order issue, no cross-pipe overlap).  So cut pipe work:
//  (1) PV at FULL rate: 16x16x32 instead of half-rate 16x16x16bf16_1k.
//      P^T relayout from S^T C-layout regs (kpos quad*4+r per 16-tile) to
//      K=32 B-frag (kpos quad*8+e) via 2x v_permlane32_swap_b32 (quad0<->2,
//      1<->3) + 4x ds_swizzle xor16 (quad0<->1,2<->3) + 4 cndmask per
//      (t, nt-pair).  Halves PV MFMA instrs + halves V-frag LDS instrs.
//  (2) Double-buffered K/V staging, counted vmcnt(8) + raw s_barrier
//      (r2-proven machinery): no per-iter vmcnt(0) drain.
// No-max softmax (|s|<=16.3 in exp2 domain, bounded by RMSNorm).
// ---------------------------------------------------------------------------
__global__ __launch_bounds__(256, 2)
void attn2(const unsigned short* __restrict__ qb,
           const unsigned short* __restrict__ kb,
           const unsigned short* __restrict__ vtb,
           unsigned short* __restrict__ ao) {
  __shared__ unsigned short kl[2][64][128];   // 2 x 16 KB : K tile (kpos x d)
  __shared__ unsigned short vl[2][128][64];   // 2 x 16 KB : V^T tile (d x kpos)

  const int tid = threadIdx.x;
  const int wave = tid >> 6, lane = tid & 63, quad = lane >> 4, lm = lane & 15;
  const int qblk = blockIdx.x & 7;
  const int bh = blockIdx.x >> 3;
  const int b = bh >> 4, h = bh & 15, kvh = h >> 2;
  const int q0 = qblk * 128 + wave * 32;
  const bool qodd = (quad & 1) != 0;

  // Q fragments (already scaled by SCALE_LOG2E at projection time)
  bf16x8 qf[2][4];
  const unsigned short* qbase = qb + ((size_t)((b * NH + h) * QL + q0)) * HD;
  #pragma unroll
  for (int t = 0; t < 2; ++t)
    #pragma unroll
    for (int kq = 0; kq < 4; ++kq)
      qf[t][kq] = *(const bf16x8*)(qbase + (t * 16 + lm) * HD + kq * 32 + quad * 8);

  f32x4 o[2][8];
  float li[2] = {0.f, 0.f};
  #pragma unroll
  for (int t = 0; t < 2; ++t)
    #pragma unroll
    for (int dt = 0; dt < 8; ++dt)
      #pragma unroll
      for (int rr = 0; rr < 4; ++rr) o[t][dt][rr] = 0.f;

  const unsigned short* kbase = kb + ((size_t)(b * NKV + kvh)) * KL * HD;
  const unsigned short* vbase = vtb + ((size_t)(b * NKV + kvh)) * HD * KL;

  // per-thread staging granule (XOR swizzle; granule i at fixed XOR because
  // row advances by multiples of 8 across i)
  const int krow0 = tid >> 4, kgc = tid & 15;
  const int kgg = (kgc & 8) | ((kgc & 7) ^ (krow0 & 7));
  const unsigned short* kgp0 = kbase + (size_t)krow0 * HD + kgg * 8;
  const int vrow0 = tid >> 3;
  const int vgv = (tid & 7) ^ (vrow0 & 7);
  const unsigned short* vgp0 = vbase + (size_t)vrow0 * KL + vgv * 8;

  auto stage = [&](int bufi, int ktt) {
    #pragma unroll
    for (int i = 0; i < 4; ++i) {
      async16(kgp0 + (size_t)ktt * (64 * HD) + i * (16 * HD),
              (char*)&kl[bufi][0][0] + (i * 256 + wave * 64) * 16);
      async16(vgp0 + (size_t)ktt * 64 + i * (32 * KL),
              (char*)&vl[bufi][0][0] + (i * 256 + wave * 64) * 16);
    }
  };

  stage(0, 0);
  for (int kt = 0; kt < KL / 64; ++kt) {
    const int cur = kt & 1;
    if (kt + 1 < KL / 64) {
      stage(cur ^ 1, kt + 1);                            // 8 loads in flight
      asm volatile("s_waitcnt vmcnt(8)" ::: "memory");   // wait only cur's 8
    } else {
      asm volatile("s_waitcnt vmcnt(0)" ::: "memory");
    }
    __builtin_amdgcn_s_barrier();

    #pragma unroll
    for (int j = 0; j < 2; ++j) {        // pair of 16-kpos column tiles
      unsigned pk[2][2][2];              // [t][sub][half]: 2 bf16 each
      #pragma unroll
      for (int sub = 0; sub < 2; ++sub) {
        const int nt = j * 2 + sub;
        bf16x8 kf[4];
        #pragma unroll
        for (int kq = 0; kq < 4; ++kq) {
          const int gc = kq * 4 + quad;
          const int swz = (gc & 8) | ((gc & 7) ^ (lm & 7));
          kf[kq] = *(const bf16x8*)&kl[cur][nt * 16 + lm][swz * 8];
        }
        f32x4 s0 = {0.f, 0.f, 0.f, 0.f}, s1 = {0.f, 0.f, 0.f, 0.f};
        __builtin_amdgcn_s_setprio(1);
        #pragma unroll
        for (int kq = 0; kq < 4; ++kq) {
          s0 = __builtin_amdgcn_mfma_f32_16x16x32_bf16(kf[kq], qf[0][kq], s0, 0, 0, 0);
          s1 = __builtin_amdgcn_mfma_f32_16x16x32_bf16(kf[kq], qf[1][kq], s1, 0, 0, 0);
        }
        __builtin_amdgcn_s_setprio(0);
        float e00 = __builtin_amdgcn_exp2f(s0[0]), e01 = __builtin_amdgcn_exp2f(s0[1]);
        float e02 = __builtin_amdgcn_exp2f(s0[2]), e03 = __builtin_amdgcn_exp2f(s0[3]);
        float e10 = __builtin_amdgcn_exp2f(s1[0]), e11 = __builtin_amdgcn_exp2f(s1[1]);
        float e12 = __builtin_amdgcn_exp2f(s1[2]), e13 = __builtin_amdgcn_exp2f(s1[3]);
        li[0] += (e00 + e01) + (e02 + e03);
        li[1] += (e10 + e11) + (e12 + e13);
        pk[0][sub][0] = mk2(e00, e01); pk[0][sub][1] = mk2(e02, e03);
        pk[1][sub][0] = mk2(e10, e11); pk[1][sub][1] = mk2(e12, e13);
      }
      // relayout: lane(quad) holds kpos quad*4+r of both subs; K=32 B-frag
      // needs kpos quad*8+e.  permlane32_swap: a'=[a.lo|b.lo], b'=[a.hi|b.hi].
      bf16x8 P[2];
      #pragma unroll
      for (int t = 0; t < 2; ++t) {
        unsigned a0 = pk[t][0][0], b0 = pk[t][1][0];
        unsigned a1 = pk[t][0][1], b1 = pk[t][1][1];
        asm volatile("v_permlane32_swap_b32 %0, %1" : "+v"(a0), "+v"(b0));
        asm volatile("v_permlane32_swap_b32 %0, %1" : "+v"(a1), "+v"(b1));
        const unsigned sa0 = __builtin_amdgcn_ds_swizzle(a0, 0x401F);  // xor 16
        const unsigned sb0 = __builtin_amdgcn_ds_swizzle(b0, 0x401F);
        const unsigned sa1 = __builtin_amdgcn_ds_swizzle(a1, 0x401F);
        const unsigned sb1 = __builtin_amdgcn_ds_swizzle(b1, 0x401F);
        union { unsigned u[4]; bf16x8 v; } up;
        up.u[0] = qodd ? sb0 : a0;
        up.u[1] = qodd ? sb1 : a1;
        up.u[2] = qodd ? b0 : sa0;
        up.u[3] = qodd ? b1 : sa1;
        P[t] = up.v;
      }
      __builtin_amdgcn_s_setprio(1);
      #pragma unroll
      for (int dt = 0; dt < 8; ++dt) {
        const int gv = (j * 4 + quad) ^ (lm & 7);
        bf16x8 vfr = *(const bf16x8*)&vl[cur][dt * 16 + lm][gv * 8];
        o[0][dt] = __builtin_amdgcn_mfma_f32_16x16x32_bf16(vfr, P[0], o[0][dt], 0, 0, 0);
        o[1][dt] = __builtin_amdgcn_mfma_f32_16x16x32_bf16(vfr, P[1], o[1][dt], 0, 0, 0);
      }
      __builtin_amdgcn_s_setprio(0);
    }
    __builtin_amdgcn_s_barrier();
  }

  #pragma unroll
  for (int t = 0; t < 2; ++t) {
    float l = li[t];
    l += __shfl_xor(l, 16);
    l += __shfl_xor(l, 32);
    const float inv = 1.0f / l;
    const size_t rowbase = ((size_t)(b * QL + q0 + t * 16 + lm)) * (NH * HD) + h * HD;
    #pragma unroll
    for (int dt = 0; dt < 8; ++dt) {
      bf16x4 v = mk4(o[t][dt][0] * inv, o[t][dt][1] * inv,
                     o[t][dt][2] * inv, o[t][dt][3] * inv);
      *(bf16x4*)(ao + rowbase + dt * 16 + quad * 4) = v;
    }
  }
}

// ---------------------------------------------------------------------------
extern "C" void kernel_launch(void* const* d_in, const int* in_sizes, int n_in,
                              void* d_out, int out_size, void* d_ws, size_t ws_size,
                              hipStream_t stream) {
  const float* noise = (const float*)d_in[0];
  const float* ctx   = (const float*)d_in[1];
  const float* cosb  = (const float*)d_in[2];
  const float* sinb  = (const float*)d_in[3];
  const float* Wq    = (const float*)d_in[4];
  const float* Wk    = (const float*)d_in[5];
  const float* Wv    = (const float*)d_in[6];
  const float* Wo    = (const float*)d_in[7];
  const float* qn    = (const float*)d_in[8];
  const float* kn    = (const float*)d_in[9];
  float* out = (float*)d_out;

  char* ws = (char*)d_ws;
  // kvin: 64 MB [0,64M).  aob aliases kvin[0:16M) (kvin dead after V-proj).
  unsigned short* kvin = (unsigned short*)(ws);
  unsigned short* aob  = (unsigned short*)(ws);
  unsigned short* WqT  = (unsigned short*)(ws + 67108864);            //  8 MB
  unsigned short* WkT  = (unsigned short*)(ws + 67108864 + 8388608);  //  2 MB
  unsigned short* WvT  = (unsigned short*)(ws + 67108864 + 10485760); //  2 MB
  unsigned short* WoT  = (unsigned short*)(ws + 67108864 + 12582912); //  8 MB
  unsigned short* qbuf = (unsigned short*)(ws + 67108864 + 20971520); // 16 MB
  unsigned short* kbuf = (unsigned short*)(ws + 67108864 + 37748736); // 16 MB
  unsigned short* vtb  = (unsigned short*)(ws + 67108864 + 54525952); // 16 MB (total 132 MB)

  prep<<<dim3((B_ * KL * H_) / 8 / 256), dim3(256), 0, stream>>>(noise, ctx, kvin);

  wtrans<<<dim3(1024), dim3(256), 0, stream>>>(Wq, WqT, 2048, 2048);
  wtrans<<<dim3(256),  dim3(256), 0, stream>>>(Wk, WkT, 2048, 512);
  wtrans<<<dim3(256),  dim3(256), 0, stream>>>(Wv, WvT, 2048, 512);
  wtrans<<<dim3(1024), dim3(256), 0, stream>>>(Wo, WoT, 2048, 2048);

  gemm2<0><<<dim3(32 * 16), dim3(256), 0, stream>>>(
      kvin, WqT, qn, cosb, sinb, qbuf, nullptr);
  gemm2<1><<<dim3(128 * 4), dim3(256), 0, stream>>>(
      kvin, WkT, kn, cosb, sinb, kbuf, nullptr);
  gemm2<2><<<dim3(128 * 4), dim3(256), 0, stream>>>(
      kvin, WvT, nullptr, nullptr, nullptr, vtb, nullptr);

  attn2<<<dim3(512), dim3(256), 0, stream>>>(qbuf, kbuf, vtb, aob);

  gemm2<3><<<dim3(32 * 16), dim3(256), 0, stream>>>(
      aob, WoT, nullptr, nullptr, nullptr, nullptr, out);
}